// Round 1
// baseline (859.551 us; speedup 1.0000x reference)
//
#include <hip/hip_runtime.h>

#define NF 26
#define NB 16384
#define NL 8
#define NV 100000
#define ND 64
#define WAVES_PER_BLOCK 4
#define BLOCK (WAVES_PER_BLOCK * 64)

__global__ __launch_bounds__(BLOCK) void fwfm_kernel(
    const int*   __restrict__ idxs,   // [F,B,L]
    const float* __restrict__ wts,    // [F,B,L]
    const float* __restrict__ emb,    // [F,V,D]
    const float* __restrict__ lin_w,  // [F*D]
    const float* __restrict__ r,      // [F,F]
    const float* __restrict__ bias,   // [1]
    float*       __restrict__ out)    // [B]
{
    __shared__ int   s_idx[WAVES_PER_BLOCK][NF * NL];
    __shared__ float s_wt [WAVES_PER_BLOCK][NF * NL];
    __shared__ float s_r  [NF * NF];

    const int tid  = threadIdx.x;
    const int wave = tid >> 6;
    const int lane = tid & 63;
    const int b0   = blockIdx.x * WAVES_PER_BLOCK;

    // stage r (676 floats)
    for (int i = tid; i < NF * NF; i += BLOCK) s_r[i] = r[i];

    // stage idx/weight for this block's 4 batch elements.
    // element e of a given b: f = e/L, l = e%L; global off = f*B*L + b*L + l
    for (int e = tid; e < WAVES_PER_BLOCK * NF * NL; e += BLOCK) {
        int w  = e / (NF * NL);
        int fe = e - w * (NF * NL);
        int f  = fe >> 3;
        int l  = fe & 7;
        int b  = b0 + w;
        size_t off = (size_t)f * (NB * NL) + (size_t)b * NL + l;
        s_idx[w][fe] = idxs[off];
        s_wt [w][fe] = wts [off];
    }
    __syncthreads();

    const int b = b0 + wave;

    float acc[NF];
    #pragma unroll
    for (int f = 0; f < NF; ++f) acc[f] = 0.f;

    // gather + weighted bag-sum: 208 coalesced 256B row loads per wave
    #pragma unroll
    for (int f = 0; f < NF; ++f) {
        const float* tbl = emb + (size_t)f * NV * ND;
        #pragma unroll
        for (int l = 0; l < NL; ++l) {
            int   ix = s_idx[wave][f * NL + l];
            float w  = s_wt [wave][f * NL + l];
            acc[f] = fmaf(w, tbl[(size_t)ix * ND + lane], acc[f]);
        }
    }

    // linear term partial (lane-local over d)
    float part = 0.f;
    #pragma unroll
    for (int f = 0; f < NF; ++f)
        part = fmaf(acc[f], lin_w[f * ND + lane], part);

    // pairwise term: sum_{f<g} r[f,g] * v_f[d] * v_g[d]
    #pragma unroll
    for (int f = 0; f < NF; ++f) {
        float s = 0.f;
        #pragma unroll
        for (int g = f + 1; g < NF; ++g)
            s = fmaf(s_r[f * NF + g], acc[g], s);
        part = fmaf(acc[f], s, part);
    }

    // reduce over 64 lanes
    #pragma unroll
    for (int off = 32; off > 0; off >>= 1)
        part += __shfl_xor(part, off, 64);

    if (lane == 0) out[b] = part + bias[0];
}

extern "C" void kernel_launch(void* const* d_in, const int* in_sizes, int n_in,
                              void* d_out, int out_size, void* d_ws, size_t ws_size,
                              hipStream_t stream) {
    const int*   idxs  = (const int*)  d_in[0];
    const float* wts   = (const float*)d_in[1];
    const float* emb   = (const float*)d_in[2];
    const float* lin_w = (const float*)d_in[3];
    const float* r     = (const float*)d_in[4];
    const float* bias  = (const float*)d_in[5];
    float* out = (float*)d_out;

    dim3 grid(NB / WAVES_PER_BLOCK);
    dim3 block(BLOCK);
    fwfm_kernel<<<grid, block, 0, stream>>>(idxs, wts, emb, lin_w, r, bias, out);
}